// Round 3
// baseline (2199.564 us; speedup 1.0000x reference)
//
#include <hip/hip_runtime.h>
#include <cstdint>
#include <cstddef>

#define DIM_D 32
#define KIN   66
#define DIM_H 256
#define NSTE  100
#define BATCHN 4096
#define ROWS  8
#define BLKT  512
#define NBLK  (BATCHN / ROWS)   // 512 blocks -> 2 blocks/CU

#define CTRL_OFF 0
#define X_OFF ((size_t)BATCHN * NSTE * DIM_D)
#define J_OFF (X_OFF + (size_t)BATCHN * NSTE * 65)

// bf16 weight arrays in d_ws (element offsets)
#define W1B_OFF 0            // [256][96] (cols 66..95 zero)
#define W2B_OFF 24576        // [256][256]
#define W3B_OFF 90112        // [256][256]
#define W4B_OFF 155648       // [32][256]
#define WS_ELEMS 163840

constexpr float DT_C = 0.01f;

typedef __bf16 bf16x8 __attribute__((ext_vector_type(8)));
typedef float  f32x4  __attribute__((ext_vector_type(4)));

__device__ __forceinline__ uint32_t rotl32(uint32_t x, int n) {
  return (x << n) | (x >> (32 - n));
}

// Threefry-2x32, 20 rounds — matches jax partitionable path (verified round 1)
__device__ __forceinline__ void tf2x32(uint32_t k0, uint32_t k1,
                                       uint32_t x0, uint32_t x1,
                                       uint32_t& o0, uint32_t& o1) {
  uint32_t k2 = k0 ^ k1 ^ 0x1BD11BDAu;
#define TFR(r) { x0 += x1; x1 = rotl32(x1, (r)); x1 ^= x0; }
  x0 += k0; x1 += k1;
  TFR(13) TFR(15) TFR(26) TFR(6)   x0 += k1; x1 += k2 + 1u;
  TFR(17) TFR(29) TFR(16) TFR(24)  x0 += k2; x1 += k0 + 2u;
  TFR(13) TFR(15) TFR(26) TFR(6)   x0 += k0; x1 += k1 + 3u;
  TFR(17) TFR(29) TFR(16) TFR(24)  x0 += k1; x1 += k2 + 4u;
  TFR(13) TFR(15) TFR(26) TFR(6)   x0 += k2; x1 += k0 + 5u;
#undef TFR
  o0 = x0; o1 = x1;
}

__global__ void conv_w(const float* __restrict__ W1, const float* __restrict__ W2,
                       const float* __restrict__ W3, const float* __restrict__ W4,
                       __bf16* __restrict__ ws) {
  int t = blockIdx.x * 256 + threadIdx.x;
  if (t < W2B_OFF) {
    int r = t / 96, c = t % 96;
    ws[t] = (c < KIN) ? (__bf16)W1[r * KIN + c] : (__bf16)0.0f;
  } else if (t < W3B_OFF) {
    ws[t] = (__bf16)W2[t - W2B_OFF];
  } else if (t < W4B_OFF) {
    ws[t] = (__bf16)W3[t - W3B_OFF];
  } else if (t < WS_ELEMS) {
    ws[t] = (__bf16)W4[t - W4B_OFF];
  }
}

__device__ __forceinline__ f32x4 mfma16(bf16x8 a, bf16x8 b, f32x4 c) {
  return __builtin_amdgcn_mfma_f32_16x16x32_bf16(a, b, c, 0, 0, 0);
}

// XOR-swizzled LDS byte offsets (col is a BYTE offset within the row)
__device__ __forceinline__ int swz256(int row, int col) { return row * 256 + (col ^ ((row & 15) << 4)); }
__device__ __forceinline__ int swz512(int row, int col) { return row * 512 + (col ^ ((row & 15) << 4)); }

__global__ __launch_bounds__(BLKT, 4) void model_kernel(
    const __bf16* __restrict__ ws,
    const float* __restrict__ b1, const float* __restrict__ b2,
    const float* __restrict__ b3, const float* __restrict__ b4,
    const float* __restrict__ x0p, const float* __restrict__ sp,
    const float* __restrict__ dpp, float* __restrict__ out)
{
  __shared__ __bf16 xb[16 * 128];       // MLP input (bf16, swizzled); rows 8-15 zero
  __shared__ __bf16 zA[16 * 256];       // L1 out
  __shared__ __bf16 zB[16 * 256];       // L2 out
  __shared__ __bf16 scr[8 * 16 * 56];   // per-wave L3->L4 transpose scratch (112B row stride)
  __shared__ float  psum[8][8][32];     // L4 K-split partials (valid rows only)
  __shared__ uint32_t keys[NSTE - 1][2];
  __shared__ uint32_t jb[NSTE - 1][8];  // jump bitmask per (step, row)

  const int tid = threadIdx.x;
  const int r0  = blockIdx.x * ROWS;
  char* xbB = (char*)xb;
  char* zAB = (char*)zA;
  char* zBB = (char*)zB;

  const int wv  = tid >> 6;      // wave 0..7 -> N-cols [wv*32, wv*32+32)
  const int ln  = tid & 63;
  const int lr  = ln & 15;
  const int g   = ln >> 4;
  const int lk8 = g * 8;
  const int er  = tid >> 5, ed = tid & 31;   // epilogue (row, dim), tid<256

  // ---------------- phase A: keys + zero xb ----------------
  if (tid < NSTE - 1) {
    uint32_t o0, o1;
    tf2x32(0u, 1234u, 0u, (uint32_t)tid, o0, o1);   // fold_in(key(1234), n)
    keys[tid][0] = o0; keys[tid][1] = o1;
  }
  for (int i = tid; i < 16 * 128; i += BLKT) xb[i] = (__bf16)0.0f;
  const float dp = dpp[0];
  __syncthreads();

  // ---------------- phase B: jump-bit precompute + state init + frags ----------------
  {
    const int rr = ((wv & 3) << 1) + (ln >> 5);     // row 0..7
    const int dd = ln & 31;
    const uint32_t F = (uint32_t)((r0 + rr) * DIM_D + dd);
    const int n0 = (wv >> 2) * 50;
    const int n1 = (wv >> 2) ? (NSTE - 1) : 50;
    for (int n = n0; n < n1; ++n) {
      uint32_t o0, o1;
      tf2x32(keys[n][0], keys[n][1], 0u, F, o0, o1);
      const uint32_t bits = o0 ^ o1;
      const float uf = __uint_as_float((bits >> 9) | 0x3f800000u) - 1.0f;
      const unsigned long long m = __ballot(uf < 0.05f);
      if (ln == 0)       jb[n][rr] = (uint32_t)m;
      else if (ln == 32) jb[n][rr] = (uint32_t)(m >> 32);
    }
  }

  float V = 0.f, cr = 0.f, hv = 0.f, vsum = 0.f, hD = 0.f, s_d = 1.f, b4d = 0.f;
  size_t ctrlb = 0, xbase = 0;
  if (tid < 256) {
    s_d = sp[ed];
    b4d = b4[ed];
    V  = x0p[ed];
    cr = x0p[33 + ed];
    hv = -logf(1.0f - V) / s_d;
    ctrlb = CTRL_OFF + (size_t)(r0 + er) * NSTE * DIM_D;
    xbase = X_OFF + (size_t)(r0 + er) * NSTE * 65;
    // xb state (rows 0..7)
    *(__bf16*)(xbB + swz256(er, ed * 2))        = (__bf16)V;
    *(__bf16*)(xbB + swz256(er, (33 + ed) * 2)) = (__bf16)cr;
    // outputs: x_tensor[:,0,:] and control[:,99,:] = 0
    out[xbase + ed] = V;
    out[xbase + 33 + ed] = cr;
    out[ctrlb + (size_t)(NSTE - 1) * DIM_D + ed] = 0.0f;
    if (ed == 0) {
      hD = x0p[DIM_D] / dp;
      *(__bf16*)(xbB + swz256(er, 64))  = (__bf16)x0p[DIM_D];  // col 32 = Dv0
      *(__bf16*)(xbB + swz256(er, 130)) = (__bf16)0.0f;        // col 65 = t = 0
      out[xbase + 32] = x0p[DIM_D];
    }
  }

  // weight fragments (compiler keeps what fits in 128 VGPR, reloads rest from L2)
  bf16x8 w1f[2][3], w2f[2][8], w3f[2][8], w4t[2];
#pragma unroll
  for (int t = 0; t < 2; ++t) {
    const int n1c = wv * 32 + t * 16 + lr;
#pragma unroll
    for (int ks = 0; ks < 3; ++ks)
      w1f[t][ks] = *(const bf16x8*)(ws + W1B_OFF + n1c * 96 + ks * 32 + lk8);
#pragma unroll
    for (int ks = 0; ks < 8; ++ks) {
      w2f[t][ks] = *(const bf16x8*)(ws + W2B_OFF + n1c * 256 + ks * 32 + lk8);
      w3f[t][ks] = *(const bf16x8*)(ws + W3B_OFF + n1c * 256 + ks * 32 + lk8);
    }
    // L4 B-frag: wave's own 32-col K-chunk, N-tile t
    w4t[t] = *(const bf16x8*)(ws + W4B_OFF + (t * 16 + lr) * 256 + wv * 32 + lk8);
  }
  const float bb1_0 = b1[wv * 32 + lr], bb1_1 = b1[wv * 32 + 16 + lr];
  const float bb2_0 = b2[wv * 32 + lr], bb2_1 = b2[wv * 32 + 16 + lr];
  const float bb3_0 = b3[wv * 32 + lr], bb3_1 = b3[wv * 32 + 16 + lr];
  __syncthreads();

  float u_s = 0.f, V_s = 0.f, cr_s = 0.f, Dv_s = 0.f;

  // ---------------- 99 steps ----------------
  for (int n = 0; n < NSTE - 1; ++n) {
    // deferred global stores for step n-1 (drain hides under L1)
    if (n > 0 && tid < 256) {
      out[ctrlb + (size_t)(n - 1) * DIM_D + ed] = u_s;
      const size_t xo = xbase + (size_t)n * 65;
      out[xo + ed] = V_s;
      out[xo + 33 + ed] = cr_s;
      if (ed == 0) out[xo + 32] = Dv_s;
    }

    // ---- L1: xb (K=96) -> zA ----
    {
      f32x4 a0 = {bb1_0, bb1_0, bb1_0, bb1_0};
      f32x4 a1 = {bb1_1, bb1_1, bb1_1, bb1_1};
      f32x4 a0o = {0, 0, 0, 0}, a1o = {0, 0, 0, 0};
      bf16x8 af0 = *(const bf16x8*)(xbB + swz256(lr, g * 16));
      bf16x8 af1 = *(const bf16x8*)(xbB + swz256(lr, 64 + g * 16));
      bf16x8 af2 = *(const bf16x8*)(xbB + swz256(lr, 128 + g * 16));
      a0  = mfma16(af0, w1f[0][0], a0);  a1  = mfma16(af0, w1f[1][0], a1);
      a0o = mfma16(af1, w1f[0][1], a0o); a1o = mfma16(af1, w1f[1][1], a1o);
      a0  = mfma16(af2, w1f[0][2], a0);  a1  = mfma16(af2, w1f[1][2], a1);
      a0 += a0o; a1 += a1o;
#pragma unroll
      for (int q = 0; q < 4; ++q) {
        const int row = g * 4 + q;
        *(__bf16*)(zAB + swz512(row, (wv * 32 + lr) * 2))      = (__bf16)fmaxf(a0[q], 0.0f);
        *(__bf16*)(zAB + swz512(row, (wv * 32 + 16 + lr) * 2)) = (__bf16)fmaxf(a1[q], 0.0f);
      }
    }
    __syncthreads();

    // ---- L2: zA -> zB ----
    {
      f32x4 a0 = {bb2_0, bb2_0, bb2_0, bb2_0};
      f32x4 a1 = {bb2_1, bb2_1, bb2_1, bb2_1};
      f32x4 a0o = {0, 0, 0, 0}, a1o = {0, 0, 0, 0};
#pragma unroll
      for (int ks = 0; ks < 8; ks += 2) {
        bf16x8 afe = *(const bf16x8*)(zAB + swz512(lr, ks * 64 + g * 16));
        a0  = mfma16(afe, w2f[0][ks], a0);
        a1  = mfma16(afe, w2f[1][ks], a1);
        bf16x8 afo = *(const bf16x8*)(zAB + swz512(lr, (ks + 1) * 64 + g * 16));
        a0o = mfma16(afo, w2f[0][ks + 1], a0o);
        a1o = mfma16(afo, w2f[1][ks + 1], a1o);
      }
      a0 += a0o; a1 += a1o;
#pragma unroll
      for (int q = 0; q < 4; ++q) {
        const int row = g * 4 + q;
        *(__bf16*)(zBB + swz512(row, (wv * 32 + lr) * 2))      = (__bf16)fmaxf(a0[q], 0.0f);
        *(__bf16*)(zBB + swz512(row, (wv * 32 + 16 + lr) * 2)) = (__bf16)fmaxf(a1[q], 0.0f);
      }
    }
    __syncthreads();

    // ---- L3 (zB -> regs) fused with L4 (no block barrier between) ----
    {
      f32x4 a0 = {bb3_0, bb3_0, bb3_0, bb3_0};
      f32x4 a1 = {bb3_1, bb3_1, bb3_1, bb3_1};
      f32x4 a0o = {0, 0, 0, 0}, a1o = {0, 0, 0, 0};
#pragma unroll
      for (int ks = 0; ks < 8; ks += 2) {
        bf16x8 afe = *(const bf16x8*)(zBB + swz512(lr, ks * 64 + g * 16));
        a0  = mfma16(afe, w3f[0][ks], a0);
        a1  = mfma16(afe, w3f[1][ks], a1);
        bf16x8 afo = *(const bf16x8*)(zBB + swz512(lr, (ks + 1) * 64 + g * 16));
        a0o = mfma16(afo, w3f[0][ks + 1], a0o);
        a1o = mfma16(afo, w3f[1][ks + 1], a1o);
      }
      a0 += a0o; a1 += a1o;
      // intra-wave transpose of this wave's 32 cols through private scratch
      char* sw = (char*)scr + wv * 1792;
#pragma unroll
      for (int q = 0; q < 4; ++q) {
        const int row = g * 4 + q;
        *(__bf16*)(sw + row * 112 + lr * 2)      = (__bf16)fmaxf(a0[q], 0.0f);
        *(__bf16*)(sw + row * 112 + 32 + lr * 2) = (__bf16)fmaxf(a1[q], 0.0f);
      }
      asm volatile("s_waitcnt lgkmcnt(0)" ::: "memory");   // wave-local visibility
      const bf16x8 a4 = *(const bf16x8*)(sw + lr * 112 + g * 16);
      f32x4 c0 = {0, 0, 0, 0}, c1 = {0, 0, 0, 0};
      c0 = mfma16(a4, w4t[0], c0);
      c1 = mfma16(a4, w4t[1], c1);
      if (g < 2) {
#pragma unroll
        for (int q = 0; q < 4; ++q) {
          psum[wv][g * 4 + q][lr]      = c0[q];
          psum[wv][g * 4 + q][16 + lr] = c1[q];
        }
      }
    }
    __syncthreads();

    // ---- epilogue: u = sigmoid(b4 + sum psum), jump, state update (regs) ----
    if (tid < 256) {
      vsum += V;                         // f-accumulation with pre-update V
      float up = b4d;
#pragma unroll
      for (int w = 0; w < 8; ++w) up += psum[w][er][ed];
      const float u = 1.0f / (1.0f + __expf(-up));
      const bool jump = (jb[n][er] >> ed) & 1;
      hv = jump ? 0.0f : (hv + DT_C);
      cr += jump ? u : 0.0f;
      V = 1.0f - __expf(-s_d * hv);
      *(__bf16*)(xbB + swz256(er, ed * 2))        = (__bf16)V;
      *(__bf16*)(xbB + swz256(er, (33 + ed) * 2)) = (__bf16)cr;
      if (ed == 0) {
        hD += DT_C;
        Dv_s = dp * hD;
        *(__bf16*)(xbB + swz256(er, 64))  = (__bf16)Dv_s;
        *(__bf16*)(xbB + swz256(er, 130)) = (__bf16)(DT_C * (float)(n + 1));
      }
      u_s = u; V_s = V; cr_s = cr;
    }
    __syncthreads();
  }

  // ---- final stores (step 98) + J ----
  if (tid < 256) {
    out[ctrlb + (size_t)(NSTE - 2) * DIM_D + ed] = u_s;
    const size_t xo = xbase + (size_t)(NSTE - 1) * 65;
    out[xo + ed] = V_s;
    out[xo + 33 + ed] = cr_s;
    if (ed == 0) out[xo + 32] = Dv_s;

    float c = cr, vv = vsum;
#pragma unroll
    for (int m = 1; m < 32; m <<= 1) {
      c  += __shfl_xor(c,  m, 32);
      vv += __shfl_xor(vv, m, 32);
    }
    if (ed == 0) out[J_OFF + (size_t)(r0 + er)] = DT_C * vv + c;
  }
}

extern "C" void kernel_launch(void* const* d_in, const int* in_sizes, int n_in,
                              void* d_out, int out_size, void* d_ws, size_t ws_size,
                              hipStream_t stream) {
  const float* W1 = (const float*)d_in[0];
  const float* b1 = (const float*)d_in[1];
  const float* W2 = (const float*)d_in[2];
  const float* b2 = (const float*)d_in[3];
  const float* W3 = (const float*)d_in[4];
  const float* b3 = (const float*)d_in[5];
  const float* W4 = (const float*)d_in[6];
  const float* b4 = (const float*)d_in[7];
  const float* x0 = (const float*)d_in[8];
  const float* s  = (const float*)d_in[9];
  const float* dp = (const float*)d_in[10];
  __bf16* ws = (__bf16*)d_ws;
  float* out = (float*)d_out;

  hipLaunchKernelGGL(conv_w, dim3(WS_ELEMS / 256), dim3(256), 0, stream, W1, W2, W3, W4, ws);
  hipLaunchKernelGGL(model_kernel, dim3(NBLK), dim3(BLKT), 0, stream,
                     ws, b1, b2, b3, b4, x0, s, dp, out);
}

// Round 4
// 306.877 us; speedup vs baseline: 7.1676x; 7.1676x over previous
//
#include <hip/hip_runtime.h>
#include <cstdint>
#include <cstddef>

#define DIM_D 32
#define KIN   66
#define DIM_H 256
#define NSTE  100
#define BATCHN 4096
#define ROWS  16
#define BLKT  512
#define NBLK  (BATCHN / ROWS)   // 256 blocks, 1 per CU

#define CTRL_OFF 0
#define X_OFF ((size_t)BATCHN * NSTE * DIM_D)
#define J_OFF (X_OFF + (size_t)BATCHN * NSTE * 65)

// bf16 weight arrays in d_ws (element offsets)
#define W1B_OFF 0            // [256][96] (cols 66..95 zero)
#define W2B_OFF 24576        // [256][256]
#define W3B_OFF 90112        // [256][256]
#define W4B_OFF 155648       // [32][256]
#define WS_ELEMS 163840

constexpr float DT_C = 0.01f;

typedef __bf16 bf16x8 __attribute__((ext_vector_type(8)));
typedef float  f32x4  __attribute__((ext_vector_type(4)));

__device__ __forceinline__ uint32_t rotl32(uint32_t x, int n) {
  return (x << n) | (x >> (32 - n));
}

// Threefry-2x32, 20 rounds — matches jax partitionable path (verified round 1)
__device__ __forceinline__ void tf2x32(uint32_t k0, uint32_t k1,
                                       uint32_t x0, uint32_t x1,
                                       uint32_t& o0, uint32_t& o1) {
  uint32_t k2 = k0 ^ k1 ^ 0x1BD11BDAu;
#define TFR(r) { x0 += x1; x1 = rotl32(x1, (r)); x1 ^= x0; }
  x0 += k0; x1 += k1;
  TFR(13) TFR(15) TFR(26) TFR(6)   x0 += k1; x1 += k2 + 1u;
  TFR(17) TFR(29) TFR(16) TFR(24)  x0 += k2; x1 += k0 + 2u;
  TFR(13) TFR(15) TFR(26) TFR(6)   x0 += k0; x1 += k1 + 3u;
  TFR(17) TFR(29) TFR(16) TFR(24)  x0 += k1; x1 += k2 + 4u;
  TFR(13) TFR(15) TFR(26) TFR(6)   x0 += k2; x1 += k0 + 5u;
#undef TFR
  o0 = x0; o1 = x1;
}

__global__ void conv_w(const float* __restrict__ W1, const float* __restrict__ W2,
                       const float* __restrict__ W3, const float* __restrict__ W4,
                       __bf16* __restrict__ ws) {
  int t = blockIdx.x * 256 + threadIdx.x;
  if (t < W2B_OFF) {
    int r = t / 96, c = t % 96;
    ws[t] = (c < KIN) ? (__bf16)W1[r * KIN + c] : (__bf16)0.0f;
  } else if (t < W3B_OFF) {
    ws[t] = (__bf16)W2[t - W2B_OFF];
  } else if (t < W4B_OFF) {
    ws[t] = (__bf16)W3[t - W3B_OFF];
  } else if (t < WS_ELEMS) {
    ws[t] = (__bf16)W4[t - W4B_OFF];
  }
}

__device__ __forceinline__ f32x4 mfma16(bf16x8 a, bf16x8 b, f32x4 c) {
  return __builtin_amdgcn_mfma_f32_16x16x32_bf16(a, b, c, 0, 0, 0);
}

// XOR-swizzled LDS byte offsets (col is a BYTE offset within the row)
__device__ __forceinline__ int swz256(int row, int col) { return row * 256 + (col ^ ((row & 15) << 4)); }
__device__ __forceinline__ int swz512(int row, int col) { return row * 512 + (col ^ ((row & 15) << 4)); }

// waves_per_eu(2,2): pin occupancy target to 2 waves/EU so the allocator uses
// the full 256-VGPR budget and keeps all 160 VGPRs of weight frags resident.
// (launch_bounds(512,4) in round 3 -> cap 128 -> full spill to scratch: 7.3 GB
// HBM fetch, 2.2 ms. launch_bounds(512,2) in round 2 -> allocator still chose
// 128 and re-loaded frags from L2 each step.)
__global__ void __launch_bounds__(BLKT)
__attribute__((amdgpu_waves_per_eu(2, 2))) model_kernel(
    const __bf16* __restrict__ ws,
    const float* __restrict__ b1, const float* __restrict__ b2,
    const float* __restrict__ b3, const float* __restrict__ b4,
    const float* __restrict__ x0p, const float* __restrict__ sp,
    const float* __restrict__ dpp, float* __restrict__ out)
{
  __shared__ __bf16 xb[16 * 128];       // MLP input (bf16, swizzled), 256B/row
  __shared__ __bf16 zA[16 * 256];       // L1 out (512B/row, swizzled)
  __shared__ __bf16 zB[16 * 256];       // L2 out
  __shared__ __bf16 scr[8 * 16 * 40];   // per-wave L3->L4 transpose scratch (80B row stride)
  __shared__ float  psum[8][16][32];    // L4 K-split partials
  __shared__ uint32_t keys[NSTE - 1][2];
  __shared__ uint32_t jb[NSTE - 1][16]; // jump bitmask per (step, row)

  const int tid = threadIdx.x;
  const int r0  = blockIdx.x * ROWS;
  char* xbB = (char*)xb;
  char* zAB = (char*)zA;
  char* zBB = (char*)zB;

  const int wv  = tid >> 6;      // wave 0..7 -> N-cols [wv*32, wv*32+32)
  const int ln  = tid & 63;
  const int lr  = ln & 15;
  const int g   = ln >> 4;
  const int lk8 = g * 8;
  const int er  = tid >> 5, ed = tid & 31;   // epilogue (row, dim) — all 512 threads

  // ---------------- phase A: keys + zero xb ----------------
  if (tid < NSTE - 1) {
    uint32_t o0, o1;
    tf2x32(0u, 1234u, 0u, (uint32_t)tid, o0, o1);   // fold_in(key(1234), n)
    keys[tid][0] = o0; keys[tid][1] = o1;
  }
  for (int i = tid; i < 16 * 128; i += BLKT) xb[i] = (__bf16)0.0f;
  const float dp = dpp[0];
  __syncthreads();

  // ---------------- phase B: jump-bit precompute + state init + frags ----------------
  {
    const int rr = 2 * wv + (ln >> 5);              // row 0..15 (2 rows per wave)
    const int dd = ln & 31;
    const uint32_t F = (uint32_t)((r0 + rr) * DIM_D + dd);
    for (int n = 0; n < NSTE - 1; ++n) {
      uint32_t o0, o1;
      tf2x32(keys[n][0], keys[n][1], 0u, F, o0, o1);
      const uint32_t bits = o0 ^ o1;
      const float uf = __uint_as_float((bits >> 9) | 0x3f800000u) - 1.0f;
      const unsigned long long m = __ballot(uf < 0.05f);
      if (ln == 0)       jb[n][rr] = (uint32_t)m;
      else if (ln == 32) jb[n][rr] = (uint32_t)(m >> 32);
    }
  }

  float V, cr, hv, vsum = 0.f, hD = 0.f, s_d, b4d;
  size_t ctrlb, xbase;
  {
    s_d = sp[ed];
    b4d = b4[ed];
    V  = x0p[ed];
    cr = x0p[33 + ed];
    hv = -logf(1.0f - V) / s_d;
    ctrlb = CTRL_OFF + (size_t)(r0 + er) * NSTE * DIM_D;
    xbase = X_OFF + (size_t)(r0 + er) * NSTE * 65;
    *(__bf16*)(xbB + swz256(er, ed * 2))        = (__bf16)V;
    *(__bf16*)(xbB + swz256(er, (33 + ed) * 2)) = (__bf16)cr;
    out[xbase + ed] = V;
    out[xbase + 33 + ed] = cr;
    out[ctrlb + (size_t)(NSTE - 1) * DIM_D + ed] = 0.0f;
    if (ed == 0) {
      hD = x0p[DIM_D] / dp;
      *(__bf16*)(xbB + swz256(er, 64))  = (__bf16)x0p[DIM_D];  // col 32 = Dv0
      *(__bf16*)(xbB + swz256(er, 130)) = (__bf16)0.0f;        // col 65 = t = 0
      out[xbase + 32] = x0p[DIM_D];
    }
  }

  // weight fragments — fully VGPR-resident (160 VGPR)
  bf16x8 w1f[2][3], w2f[2][8], w3f[2][8], w4t[2];
#pragma unroll
  for (int t = 0; t < 2; ++t) {
    const int n1c = wv * 32 + t * 16 + lr;
#pragma unroll
    for (int ks = 0; ks < 3; ++ks)
      w1f[t][ks] = *(const bf16x8*)(ws + W1B_OFF + n1c * 96 + ks * 32 + lk8);
#pragma unroll
    for (int ks = 0; ks < 8; ++ks) {
      w2f[t][ks] = *(const bf16x8*)(ws + W2B_OFF + n1c * 256 + ks * 32 + lk8);
      w3f[t][ks] = *(const bf16x8*)(ws + W3B_OFF + n1c * 256 + ks * 32 + lk8);
    }
    // L4 B-frag: wave's own 32-col K-chunk, N-tile t
    w4t[t] = *(const bf16x8*)(ws + W4B_OFF + (t * 16 + lr) * 256 + wv * 32 + lk8);
  }
  const float bb1_0 = b1[wv * 32 + lr], bb1_1 = b1[wv * 32 + 16 + lr];
  const float bb2_0 = b2[wv * 32 + lr], bb2_1 = b2[wv * 32 + 16 + lr];
  const float bb3_0 = b3[wv * 32 + lr], bb3_1 = b3[wv * 32 + 16 + lr];
  __syncthreads();

  float u_s = 0.f, V_s = 0.f, cr_s = 0.f, Dv_s = 0.f;

  // ---------------- 99 steps ----------------
  for (int n = 0; n < NSTE - 1; ++n) {
    // deferred global stores for step n-1 (drain hides under L1)
    if (n > 0) {
      out[ctrlb + (size_t)(n - 1) * DIM_D + ed] = u_s;
      const size_t xo = xbase + (size_t)n * 65;
      out[xo + ed] = V_s;
      out[xo + 33 + ed] = cr_s;
      if (ed == 0) out[xo + 32] = Dv_s;
    }

    // ---- L1: xb (K=96) -> zA ----
    {
      f32x4 a0 = {bb1_0, bb1_0, bb1_0, bb1_0};
      f32x4 a1 = {bb1_1, bb1_1, bb1_1, bb1_1};
      f32x4 a0o = {0, 0, 0, 0}, a1o = {0, 0, 0, 0};
      bf16x8 af0 = *(const bf16x8*)(xbB + swz256(lr, g * 16));
      bf16x8 af1 = *(const bf16x8*)(xbB + swz256(lr, 64 + g * 16));
      bf16x8 af2 = *(const bf16x8*)(xbB + swz256(lr, 128 + g * 16));
      a0  = mfma16(af0, w1f[0][0], a0);  a1  = mfma16(af0, w1f[1][0], a1);
      a0o = mfma16(af1, w1f[0][1], a0o); a1o = mfma16(af1, w1f[1][1], a1o);
      a0  = mfma16(af2, w1f[0][2], a0);  a1  = mfma16(af2, w1f[1][2], a1);
      a0 += a0o; a1 += a1o;
#pragma unroll
      for (int q = 0; q < 4; ++q) {
        const int row = g * 4 + q;
        *(__bf16*)(zAB + swz512(row, (wv * 32 + lr) * 2))      = (__bf16)fmaxf(a0[q], 0.0f);
        *(__bf16*)(zAB + swz512(row, (wv * 32 + 16 + lr) * 2)) = (__bf16)fmaxf(a1[q], 0.0f);
      }
    }
    __syncthreads();

    // ---- L2: zA -> zB ----
    {
      f32x4 a0 = {bb2_0, bb2_0, bb2_0, bb2_0};
      f32x4 a1 = {bb2_1, bb2_1, bb2_1, bb2_1};
      f32x4 a0o = {0, 0, 0, 0}, a1o = {0, 0, 0, 0};
#pragma unroll
      for (int ks = 0; ks < 8; ks += 2) {
        bf16x8 afe = *(const bf16x8*)(zAB + swz512(lr, ks * 64 + g * 16));
        a0  = mfma16(afe, w2f[0][ks], a0);
        a1  = mfma16(afe, w2f[1][ks], a1);
        bf16x8 afo = *(const bf16x8*)(zAB + swz512(lr, (ks + 1) * 64 + g * 16));
        a0o = mfma16(afo, w2f[0][ks + 1], a0o);
        a1o = mfma16(afo, w2f[1][ks + 1], a1o);
      }
      a0 += a0o; a1 += a1o;
#pragma unroll
      for (int q = 0; q < 4; ++q) {
        const int row = g * 4 + q;
        *(__bf16*)(zBB + swz512(row, (wv * 32 + lr) * 2))      = (__bf16)fmaxf(a0[q], 0.0f);
        *(__bf16*)(zBB + swz512(row, (wv * 32 + 16 + lr) * 2)) = (__bf16)fmaxf(a1[q], 0.0f);
      }
    }
    __syncthreads();

    // ---- L3 (zB -> regs) fused with L4 (no block barrier between) ----
    {
      f32x4 a0 = {bb3_0, bb3_0, bb3_0, bb3_0};
      f32x4 a1 = {bb3_1, bb3_1, bb3_1, bb3_1};
      f32x4 a0o = {0, 0, 0, 0}, a1o = {0, 0, 0, 0};
#pragma unroll
      for (int ks = 0; ks < 8; ks += 2) {
        bf16x8 afe = *(const bf16x8*)(zBB + swz512(lr, ks * 64 + g * 16));
        a0  = mfma16(afe, w3f[0][ks], a0);
        a1  = mfma16(afe, w3f[1][ks], a1);
        bf16x8 afo = *(const bf16x8*)(zBB + swz512(lr, (ks + 1) * 64 + g * 16));
        a0o = mfma16(afo, w3f[0][ks + 1], a0o);
        a1o = mfma16(afo, w3f[1][ks + 1], a1o);
      }
      a0 += a0o; a1 += a1o;
      // intra-wave transpose of this wave's 32 cols through private scratch
      char* sw = (char*)scr + wv * 1280;
#pragma unroll
      for (int q = 0; q < 4; ++q) {
        const int row = g * 4 + q;
        *(__bf16*)(sw + row * 80 + lr * 2)      = (__bf16)fmaxf(a0[q], 0.0f);
        *(__bf16*)(sw + row * 80 + 32 + lr * 2) = (__bf16)fmaxf(a1[q], 0.0f);
      }
      asm volatile("s_waitcnt lgkmcnt(0)" ::: "memory");   // wave-local visibility
      const bf16x8 a4 = *(const bf16x8*)(sw + lr * 80 + g * 16);
      f32x4 c0 = {0, 0, 0, 0}, c1 = {0, 0, 0, 0};
      c0 = mfma16(a4, w4t[0], c0);
      c1 = mfma16(a4, w4t[1], c1);
#pragma unroll
      for (int q = 0; q < 4; ++q) {
        psum[wv][g * 4 + q][lr]      = c0[q];
        psum[wv][g * 4 + q][16 + lr] = c1[q];
      }
    }
    __syncthreads();

    // ---- epilogue: u = sigmoid(b4 + sum psum), jump, state update (regs) ----
    {
      vsum += V;                         // f-accumulation with pre-update V
      float up = b4d;
#pragma unroll
      for (int w = 0; w < 8; ++w) up += psum[w][er][ed];
      const float u = 1.0f / (1.0f + __expf(-up));
      const bool jump = (jb[n][er] >> ed) & 1;
      hv = jump ? 0.0f : (hv + DT_C);
      cr += jump ? u : 0.0f;
      V = 1.0f - __expf(-s_d * hv);
      *(__bf16*)(xbB + swz256(er, ed * 2))        = (__bf16)V;
      *(__bf16*)(xbB + swz256(er, (33 + ed) * 2)) = (__bf16)cr;
      if (ed == 0) {
        hD += DT_C;
        Dv_s = dp * hD;
        *(__bf16*)(xbB + swz256(er, 64))  = (__bf16)Dv_s;
        *(__bf16*)(xbB + swz256(er, 130)) = (__bf16)(DT_C * (float)(n + 1));
      }
      u_s = u; V_s = V; cr_s = cr;
    }
    __syncthreads();
  }

  // ---- final stores (step 98) + J ----
  {
    out[ctrlb + (size_t)(NSTE - 2) * DIM_D + ed] = u_s;
    const size_t xo = xbase + (size_t)(NSTE - 1) * 65;
    out[xo + ed] = V_s;
    out[xo + 33 + ed] = cr_s;
    if (ed == 0) out[xo + 32] = Dv_s;

    float c = cr, vv = vsum;
#pragma unroll
    for (int m = 1; m < 32; m <<= 1) {
      c  += __shfl_xor(c,  m, 32);
      vv += __shfl_xor(vv, m, 32);
    }
    if (ed == 0) out[J_OFF + (size_t)(r0 + er)] = DT_C * vv + c;
  }
}

extern "C" void kernel_launch(void* const* d_in, const int* in_sizes, int n_in,
                              void* d_out, int out_size, void* d_ws, size_t ws_size,
                              hipStream_t stream) {
  const float* W1 = (const float*)d_in[0];
  const float* b1 = (const float*)d_in[1];
  const float* W2 = (const float*)d_in[2];
  const float* b2 = (const float*)d_in[3];
  const float* W3 = (const float*)d_in[4];
  const float* b3 = (const float*)d_in[5];
  const float* W4 = (const float*)d_in[6];
  const float* b4 = (const float*)d_in[7];
  const float* x0 = (const float*)d_in[8];
  const float* s  = (const float*)d_in[9];
  const float* dp = (const float*)d_in[10];
  __bf16* ws = (__bf16*)d_ws;
  float* out = (float*)d_out;

  hipLaunchKernelGGL(conv_w, dim3(WS_ELEMS / 256), dim3(256), 0, stream, W1, W2, W3, W4, ws);
  hipLaunchKernelGGL(model_kernel, dim3(NBLK), dim3(BLKT), 0, stream,
                     ws, b1, b2, b3, b4, x0, s, dp, out);
}